// Round 12
// baseline (31.759 us; speedup 1.0000x reference)
//
#include <hip/hip_runtime.h>
#include <math.h>

#define LL 4096
#define BB 2048
#define NT 256                 // 4 waves; each block owns a HALF-row (2048 elems)
#define ALPHA 1.0f
#define BETA 0.5f
#define NEG_INF (-__builtin_inff())
#define POS_INF (__builtin_inff())

// Buffer: 262 chunks (rel -3..258) x 9 dwords (8 elems + 1 pad).
// Own chunk t -> buffer chunk t+3, base 9*(t+3). Logical delta d from own base:
// OFS2(d) = 9*(d>>3) + (d&7)  (arith shift -> floor) — compile-time per unrolled j.
#define CBUF 2358              // 262 * 9
#define OFS2(d) (9 * ((d) >> 3) + ((d) & 7))

// ---- DPP wave64 sum reduction (VALU pipe, no LDS/bpermute) ----
template <int CTRL, int RM>
__device__ __forceinline__ float dpp_addf(float v) {
    int s = __builtin_amdgcn_update_dpp(0, __float_as_int(v), CTRL, RM, 0xf, true);
    return v + __int_as_float(s);
}
__device__ __forceinline__ float wredf(float v) {
    v = dpp_addf<0x111, 0xf>(v);   // row_shr:1
    v = dpp_addf<0x112, 0xf>(v);   // row_shr:2
    v = dpp_addf<0x114, 0xf>(v);   // row_shr:4
    v = dpp_addf<0x118, 0xf>(v);   // row_shr:8
    v = dpp_addf<0x142, 0xa>(v);   // row_bcast:15
    v = dpp_addf<0x143, 0xc>(v);   // row_bcast:31
    return v;                      // total in lane 63
}

__global__ __launch_bounds__(NT, 8) void half_kernel(const float* __restrict__ gA,
                                                     const float* __restrict__ gB,
                                                     float4* __restrict__ ws4) {
    __shared__ float sS[CBUF];     // suffix-max within chunk
    __shared__ float sP[CBUF];     // prefix-max within chunk

    const int blk = blockIdx.x;
    const int row = blk >> 1, half = blk & 1;
    const int t = threadIdx.x;
    const float* baseA = gA + (size_t)row * LL + half * 2048;
    const float* baseB = gB + (size_t)row * LL + half * 2048;
    float* const Sb = sS + 9 * (t + 3);
    float* const Pb = sP + 9 * (t + 3);

    // ---- own-chunk loads (32 B contiguous per thread per signal) ----
    float xA[8], xB[8];
    {
        const float4* a4 = (const float4*)baseA;
        const float4* b4 = (const float4*)baseB;
        float4 v0 = a4[2 * t], v1 = a4[2 * t + 1];
        xA[0] = v0.x; xA[1] = v0.y; xA[2] = v0.z; xA[3] = v0.w;
        xA[4] = v1.x; xA[5] = v1.y; xA[6] = v1.z; xA[7] = v1.w;
        float4 u0 = b4[2 * t], u1 = b4[2 * t + 1];
        xB[0] = u0.x; xB[1] = u0.y; xB[2] = u0.z; xB[3] = u0.w;
        xB[4] = u1.x; xB[5] = u1.y; xB[6] = u1.z; xB[7] = u1.w;
    }

    // ---- fused stats; reduce NOW (low pressure); each elem counted once ----
    float se = 0.f, dtp = 0.f, na = 0.f, nb = 0.f;
#pragma unroll
    for (int j = 0; j < 8; ++j) {
        float d = xA[j] - xB[j];
        se  += d * d;
        dtp += xA[j] * xB[j];
        na  += xA[j] * xA[j];
        nb  += xB[j] * xB[j];
    }
    se = wredf(se); dtp = wredf(dtp); na = wredf(na); nb = wredf(nb);

    // ---- in-register scan -> LDS ----
    auto scan = [&](const float (&x)[8], float* S9, float* P9) -> float {
        float pp[8], ss[8];
        pp[0] = x[0];
#pragma unroll
        for (int j = 1; j < 8; ++j) pp[j] = fmaxf(pp[j - 1], x[j]);
        ss[7] = x[7];
#pragma unroll
        for (int j = 6; j >= 0; --j) ss[j] = fmaxf(ss[j + 1], x[j]);
#pragma unroll
        for (int j = 0; j < 8; ++j) { P9[j] = pp[j]; S9[j] = ss[j]; }
        return pp[7];
    };

    // ---- halo: lanes 0..5 load+scan+store 3 chunks per side, short live range ----
    auto halo = [&](const float* rb) {
        if (t < 6) {
            const int hc = (t < 3) ? (t - 3) : (253 + t);   // rel chunks -3..-1, 256..258
            const int gc = half * 256 + hc;                  // chunk index within row
            float hx[8];
            if ((unsigned)gc < 512u) {
                const float4* h4 = (const float4*)(rb + hc * 8);
                float4 h0 = h4[0], h1 = h4[1];
                hx[0] = h0.x; hx[1] = h0.y; hx[2] = h0.z; hx[3] = h0.w;
                hx[4] = h1.x; hx[5] = h1.y; hx[6] = h1.z; hx[7] = h1.w;
            } else {
#pragma unroll
                for (int j = 0; j < 8; ++j) hx[j] = NEG_INF;
            }
            float dummy = scan(hx, sS + 9 * (hc + 3), sP + 9 * (hc + 3));
            (void)dummy;
        }
    };

    // ---- branchless eval; counts on SALU via ballot/popc ----
    auto eval = [&](const float (&x)[8], float cmax, unsigned& m10, int& cnt) {
        const float Cm2 = Pb[OFS2(-9)];
        const float Cm1 = Pb[OFS2(-1)];
        const float Cp1 = Pb[OFS2(15)];
        const float Cp2 = Pb[OFS2(23)];
        const float f1 = fmaxf(Cm1, cmax);
        const float f2 = fmaxf(cmax, Cp1);
        const float g2 = fmaxf(f1, Cp1);
        const float g1 = fmaxf(g2, Cm2);
        const float g3 = fmaxf(g2, Cp2);
        const float xm1 = (half == 0 && t == 0)      ? POS_INF : Sb[OFS2(-1)];
        const float xp1 = (half == 1 && t == NT - 1) ? POS_INF : Pb[OFS2(8)];
        m10 = 0u;
#pragma unroll
        for (int j = 0; j < 8; ++j) {
            float xi = x[j];
            float xl = (j > 0) ? x[j - 1] : xm1;
            float xr = (j < 7) ? x[j + 1] : xp1;
            bool lm = (xi > xl) && (xi > xr);
            float a19 = Sb[OFS2(j - 9)];
            float b19 = Pb[OFS2(j + 9)];
            float a39 = Sb[OFS2(j - 19)];
            float b39 = Pb[OFS2(j + 19)];
            float mid19 = (j == 0) ? f1 : ((j == 7) ? f2 : cmax);
            float mid39 = (j <= 2) ? g1 : ((j <= 4) ? g2 : g3);
            float p19 = fmaxf(fmaxf(a19, b19), mid19);
            float p39 = fmaxf(fmaxf(a39, b39), mid39);
            if (lm && xi >= p19) m10 |= (1u << j);
            cnt += (int)__popcll(__ballot(lm && (xi >= p39)));   // SALU accumulate
        }
    };

    unsigned mA, mB;
    int cntA = 0, cntB = 0;
    float cmA = scan(xA, Sb, Pb);
    halo(baseA);
    __syncthreads();
    eval(xA, cmA, mA, cntA);
    __syncthreads();               // A-reads done before B scan overwrites
    float cmB = scan(xB, Sb, Pb);
    halo(baseB);
    __syncthreads();
    eval(xB, cmB, mB, cntB);

    // ---- peak-to-peak squared error (aligned positions) ----
    float p2p = 0.f;
#pragma unroll
    for (int j = 0; j < 8; ++j) {
        float av = ((mA >> j) & 1u) ? xA[j] : 0.f;
        float bv = ((mB >> j) & 1u) ? xB[j] : 0.f;
        float d = av - bv;
        p2p += d * d;
    }
    p2p = wredf(p2p);              // the only tail DPP chain

    if ((t & 63) == 63) {
        const int slot = half * 4 + (t >> 6);       // 0..7 per row
        ws4[(size_t)row * 16 + slot * 2 + 0] = make_float4(se, dtp, na, nb);
        ws4[(size_t)row * 16 + slot * 2 + 1] =
            make_float4(p2p, (float)(cntA * 4096 + cntB), 0.f, 0.f);
    }
}

__global__ __launch_bounds__(256) void reduce_kernel(const float4* __restrict__ ws4,
                                                     float* __restrict__ out) {
    __shared__ float red[4][4];
    const int r = blockIdx.x * 256 + threadIdx.x;    // 8x256 -> 2048 rows
    float s0 = 0, s1 = 0, s2 = 0, s3 = 0, s4 = 0, s5 = 0;
#pragma unroll
    for (int w = 0; w < 8; ++w) {
        float4 u = ws4[(size_t)r * 16 + w * 2 + 0];
        float4 v = ws4[(size_t)r * 16 + w * 2 + 1];
        s0 += u.x; s1 += u.y; s2 += u.z; s3 += u.w;
        s4 += v.x; s5 += v.y;
    }
    int packed = (int)s5;
    int ca = packed >> 12, cb = packed & 4095;
    float mse_i = s0 * (1.0f / LL);
    float cos_i = s1 / (sqrtf(s2) * sqrtf(s3));
    float p2p_i = s4 * (1.0f / LL);
    float custom_i = (ca != cb) ? (mse_i * ALPHA) : (p2p_i * BETA);
    const float invB = 1.0f / (float)BB;
    float v0 = mse_i * invB + custom_i;   // -> total_loss
    float v1 = cos_i * invB;              // -> mean cosine
    float v2 = p2p_i;                     // -> p2p_loss
    float v3 = mse_i * invB;              // -> mse_loss
    v0 = wredf(v0); v1 = wredf(v1); v2 = wredf(v2); v3 = wredf(v3);
    int w = threadIdx.x >> 6, lane = threadIdx.x & 63;
    if (lane == 63) { red[w][0] = v0; red[w][1] = v1; red[w][2] = v2; red[w][3] = v3; }
    __syncthreads();
    if (threadIdx.x == 0) {
        float a0 = 0, a1 = 0, a2 = 0, a3 = 0;
#pragma unroll
        for (int i = 0; i < 4; ++i) {
            a0 += red[i][0]; a1 += red[i][1]; a2 += red[i][2]; a3 += red[i][3];
        }
        atomicAdd(out + 0, a0);   // 8 blocks x 4 adds — negligible contention
        atomicAdd(out + 1, a1);
        atomicAdd(out + 2, a2);
        atomicAdd(out + 3, a3);
    }
}

extern "C" void kernel_launch(void* const* d_in, const int* in_sizes, int n_in,
                              void* d_out, int out_size, void* d_ws, size_t ws_size,
                              hipStream_t stream) {
    const float* inA = (const float*)d_in[0];   // in_signal
    const float* inB = (const float*)d_in[1];   // ref_signal
    float* out = (float*)d_out;
    float4* ws4 = (float4*)d_ws;                // 2048 x 16 float4 = 512 KiB partials

    hipMemsetAsync(out, 0, out_size * sizeof(float), stream);
    hipLaunchKernelGGL(half_kernel, dim3(BB * 2), dim3(NT), 0, stream, inA, inB, ws4);
    hipLaunchKernelGGL(reduce_kernel, dim3(8), dim3(256), 0, stream, ws4, out);
}